// Round 3
// 822.882 us; speedup vs baseline: 1.2833x; 1.2833x over previous
//
#include <hip/hip_runtime.h>
#include <stdint.h>

// ---- problem constants ----
#define NAtoms   50000
#define NEdges   200000
#define NSubs    1000000
#define KP1      776      // k_elin1 LDS row pitch (bf16 elems), K=768: 1552 B = odd*16
#define GCH      32       // k_gate chunk rows (fp32 tile in LDS)

// dtype model (validated): float tensors fp32, indices int32, OUTPUT fp32.

typedef short  s16x8 __attribute__((ext_vector_type(8)));
typedef unsigned short u16x8 __attribute__((ext_vector_type(8)));
typedef float  f32x4 __attribute__((ext_vector_type(4)));

__device__ __forceinline__ float bf2f(unsigned short u) {
    union { unsigned int i; float f; } v; v.i = ((unsigned int)u) << 16; return v.f;
}
// manual RNE (kept for k_prep; bit-identical to HW cvt)
__device__ __forceinline__ unsigned short f2bf(float f) {
    union { float f; unsigned int i; } v; v.f = f;
    unsigned int x = v.i;
    unsigned int r = (x + 0x7fffu + ((x >> 16) & 1u)) >> 16;   // RNE
    return (unsigned short)r;
}
// HW conversion: compiles to v_cvt_pk_bf16_f32 (RNE) on gfx950
__device__ __forceinline__ unsigned short f2bf_hw(float f) {
    union { __bf16 h; unsigned short u; } v; v.h = (__bf16)f; return v.u;
}
__device__ __forceinline__ s16x8 pk_bf16x8(f32x4 a, f32x4 b) {
    union { u16x8 u; s16x8 s; } o;
    o.u[0] = f2bf_hw(a[0]); o.u[1] = f2bf_hw(a[1]); o.u[2] = f2bf_hw(a[2]); o.u[3] = f2bf_hw(a[3]);
    o.u[4] = f2bf_hw(b[0]); o.u[5] = f2bf_hw(b[1]); o.u[6] = f2bf_hw(b[2]); o.u[7] = f2bf_hw(b[3]);
    return o.s;
}

// async global -> LDS, 16 B per lane; dest is wave-uniform base + lane*16
typedef const __attribute__((address_space(1))) void* as1_cvp;
typedef __attribute__((address_space(3))) void* as3_vp;
__device__ __forceinline__ void gll16(const void* g, void* l) {
    __builtin_amdgcn_global_load_lds((as1_cvp)g, (as3_vp)l, 16, 0, 0);
}

// ---------------- K0: fp32 weights -> bf16 n-major layouts in ws ----------------
__global__ void k_prep(const float* __restrict__ Wf, const float* __restrict__ Ws,
                       const float* __restrict__ W1, const float* __restrict__ W2,
                       unsigned short* __restrict__ WTfs, unsigned short* __restrict__ WT1,
                       unsigned short* __restrict__ WT2) {
    int id = blockIdx.x * 256 + threadIdx.x;
    if (id < 32768) {
        int k = id & 255, n = id >> 8;
        WTfs[n * 256 + k] = f2bf((n < 64) ? Wf[k * 64 + n] : Ws[k * 64 + (n - 64)]);
    } else if (id < 131072) {
        int m = id - 32768;                  // [0, 98304) = 128 n * 768 k
        int n = m / 768, k = m - n * 768;
        int seg = k >> 8, kk = k & 255;
        float w = (kk < 240) ? W1[kk * 128 + n] : 0.0f;
        unsigned short hi = f2bf(w);
        WT1[n * 768 + k] = (seg < 2) ? hi : f2bf(w - bf2f(hi));
    } else if (id < 149504) {
        int m = id - 131072;                 // [0, 18432) = 144 n * 128 k
        int k = m & 127, n = m >> 7;
        WT2[n * 128 + k] = f2bf(W2[k * 144 + n]);
    }
}

// ---------------- K1: async fp32 staging -> swizzled LDS -> bf16 MFMA gate -> atomic scatter ----
// z-tile staged fp32 via global_load_lds (1 row = 1 KiB = 64 lanes x 16 B).
// Swizzle (rule 21, both-sides): lane fetches logical granule (lane ^ (row&7));
// reader accesses granule (g ^ (row&7)). -> fragment reads keep all 32 banks busy.
__global__ __launch_bounds__(256) void k_gate(
    const float* __restrict__ atom, const float* __restrict__ edge,
    const int* __restrict__ sai, const int* __restrict__ sei,
    const float* __restrict__ ang, const int* __restrict__ sidx_g,
    const float* __restrict__ dist,
    const float* __restrict__ bfv, const float* __restrict__ bsv,
    const unsigned short* __restrict__ WTfs, float* __restrict__ aggf) {
    __shared__ __align__(16) float ztf[GCH * 256];   // 32 KiB fp32 tile
    __shared__ float decf[GCH];
    __shared__ int   sidx[GCH];

    const int t = threadIdx.x;
    const int w = t >> 6;          // wave id: owns F cols [16w,16w+16) and S cols [64+16w,...)
    const int l = t & 63;
    const int l15 = l & 15, q = l >> 4;
    const int rowBlock = blockIdx.x << 8;   // 256 rows per block

    // B fragments cached in registers/AGPRs for the whole block
    s16x8 bF[8], bS[8];
    {
        const unsigned short* pf = WTfs + (w * 16 + l15) * 256 + q * 8;
        const unsigned short* ps = WTfs + (64 + w * 16 + l15) * 256 + q * 8;
#pragma unroll
        for (int kb = 0; kb < 8; ++kb) {
            bF[kb] = *(const s16x8*)(pf + kb * 32);
            bS[kb] = *(const s16x8*)(ps + kb * 32);
        }
    }
    const float bfj = bfv[w * 16 + l15];
    const float bsj = bsv[w * 16 + l15];

    for (int c = 0; c < 8; ++c) {
        const int chunkBase = rowBlock + c * GCH;

        // ---- phase A: burst wave-uniform index loads (s_load, lgkmcnt) ----
        int sA[8], i0A[8], i1A[8], e2A[8];
#pragma unroll
        for (int p = 0; p < 8; ++p) {
            int s = chunkBase + w * 8 + p;
            s = (s < NSubs) ? s : (NSubs - 1);          // clamp: loads always valid
            s = __builtin_amdgcn_readfirstlane(s);
            sA[p] = s;
            i0A[p] = sai[2 * s];
            i1A[p] = sai[2 * s + 1];
            e2A[p] = sei[s];
        }
        // ---- phase B: burst 8 async global_load_lds (this wave stages rows w*8..w*8+7) ----
#pragma unroll
        for (int p = 0; p < 8; ++p) {
            const int lr = w * 8 + p;
            const int G = l ^ (lr & 7);                 // pre-swizzled source granule
            const float* srcA = atom + (size_t)i0A[p] * 64  + (G      ) * 4;
            const float* srcB = atom + (size_t)i1A[p] * 64  + (G - 16 ) * 4;
            const float* srcC = edge + (size_t)e2A[p] * 112 + (G - 32 ) * 4;
            const float* srcD = ang  + (size_t)sA[p]  * 16  + (G - 60 ) * 4;
            const float* src = (G < 16) ? srcA : (G < 32) ? srcB : (G < 60) ? srcC : srcD;
            gll16(src, &ztf[lr * 256]);
            // per-row epilogue scalars (uniform s_loads)
            float d = dist[e2A[p]];
            float dc = __expf(-d * d * (1.0f / 18.0f));
            int sv = sidx_g[sA[p]];
            if (l == 0) { decf[lr] = dc; sidx[lr] = sv; }
        }
        asm volatile("s_waitcnt vmcnt(0)" ::: "memory");
        __syncthreads();

        // ---- MFMA: 2 m-batches of 16 rows; cvt fp32->bf16 in-register (HW cvt_pk) ----
#pragma unroll
        for (int mb = 0; mb < 2; ++mb) {
            f32x4 aF = {0.f, 0.f, 0.f, 0.f}, aS = {0.f, 0.f, 0.f, 0.f};
            const int row = mb * 16 + l15;
            const int sw = row & 7;
            const float* zrow = ztf + row * 256;
#pragma unroll
            for (int kb = 0; kb < 8; ++kb) {
                const int g0 = kb * 8 + q * 2;
                f32x4 x0 = *(const f32x4*)(zrow + (((g0    ) ^ sw) << 2));
                f32x4 x1 = *(const f32x4*)(zrow + (((g0 + 1) ^ sw) << 2));
                s16x8 a = pk_bf16x8(x0, x1);
                aF = __builtin_amdgcn_mfma_f32_16x16x32_bf16(a, bF[kb], aF, 0, 0, 0);
                aS = __builtin_amdgcn_mfma_f32_16x16x32_bf16(a, bS[kb], aS, 0, 0, 0);
            }
#pragma unroll
            for (int r = 0; r < 4; ++r) {
                int lr = mb * 16 + q * 4 + r;
                int s = chunkBase + lr;
                if (s < NSubs) {
                    float xf = aF[r] + bfj;
                    float xs = aS[r] + bsj;
                    float sig = __builtin_amdgcn_rcpf(1.0f + __expf(-xf));
                    float sp  = (xs > 20.0f) ? xs : __logf(1.0f + __expf(xs));
                    float val = sig * sp * decf[lr];
                    unsafeAtomicAdd(aggf + (size_t)sidx[lr] * 64 + (w * 16 + l15), val);
                }
            }
        }
        __syncthreads();
    }
}

// ---------------- K2: h=[agg|agg|edge] -> bf16x3 -> silu(h@W1+b1) -> hid(bf16) ----------------
// A row (K=768): [h_hi(256) | h_lo(256) | h_hi(256)], h = [aggf 128 | edge 112 | 0 pad 16]
__global__ __launch_bounds__(256) void k_elin1(
    const float* __restrict__ aggf, const float* __restrict__ edge,
    const unsigned short* __restrict__ WT1, const float* __restrict__ b1,
    unsigned short* __restrict__ hid) {
    __shared__ __align__(16) unsigned short zt[32 * KP1];

    const int t = threadIdx.x;
    const int w = t >> 6;
    const int l = t & 63;
    const int l15 = l & 15, q = l >> 4;
    const int rowBlock = blockIdx.x << 7;   // 128 rows per block

    const float b1a = b1[w * 16 + l15];
    const float b1b = b1[64 + w * 16 + l15];

    const int cg = t & 31;                  // column-group: loop-invariant per thread
    const int g  = t >> 5;

    for (int c = 0; c < 4; ++c) {
        const int chunkBase = rowBlock + c * 32;
        // ---- stage 32 rows: burst all 8 loads into regs, then convert ----
        f32x4 v0a[4], v1a[4];
#pragma unroll
        for (int i = 0; i < 4; ++i) {
            int lr = i * 8 + g;
            int e = chunkBase + lr;
            int ec = (e < NEdges) ? e : (NEdges - 1);   // clamp: loads always valid
            f32x4 v0 = {0.f, 0.f, 0.f, 0.f}, v1 = {0.f, 0.f, 0.f, 0.f};
            if (cg < 16) {
                const float* src = aggf + (size_t)ec * 128 + cg * 8;
                v0 = *(const f32x4*)src; v1 = *(const f32x4*)(src + 4);
            } else if (cg < 30) {
                const float* src = edge + (size_t)ec * 112 + (cg - 16) * 8;
                v0 = *(const f32x4*)src; v1 = *(const f32x4*)(src + 4);
            }
            v0a[i] = v0; v1a[i] = v1;
        }
#pragma unroll
        for (int i = 0; i < 4; ++i) {
            int lr = i * 8 + g;
            u16x8 hi, lo;
#pragma unroll
            for (int j = 0; j < 4; ++j) {
                hi[j] = f2bf_hw(v0a[i][j]);     lo[j] = f2bf_hw(v0a[i][j] - bf2f(hi[j]));
                hi[4 + j] = f2bf_hw(v1a[i][j]); lo[4 + j] = f2bf_hw(v1a[i][j] - bf2f(hi[4 + j]));
            }
            unsigned short* zrow = zt + lr * KP1;
            *(u16x8*)(zrow + cg * 8) = hi;
            *(u16x8*)(zrow + 256 + cg * 8) = lo;
            *(u16x8*)(zrow + 512 + cg * 8) = hi;
        }
        __syncthreads();
        // ---- MFMA: 2 m-batches of 16 rows, K=768; B-frags streamed from global (L1/L2) ----
#pragma unroll
        for (int mb = 0; mb < 2; ++mb) {
            f32x4 aA = {0.f, 0.f, 0.f, 0.f}, aB = {0.f, 0.f, 0.f, 0.f};
            const unsigned short* zb = zt + (mb * 16 + l15) * KP1 + q * 8;
            const unsigned short* pa = WT1 + (w * 16 + l15) * 768 + q * 8;
            const unsigned short* pb = WT1 + (64 + w * 16 + l15) * 768 + q * 8;
#pragma unroll
            for (int kb = 0; kb < 24; ++kb) {
                s16x8 a  = *(const s16x8*)(zb + kb * 32);
                s16x8 ba = *(const s16x8*)(pa + kb * 32);
                s16x8 bb = *(const s16x8*)(pb + kb * 32);
                aA = __builtin_amdgcn_mfma_f32_16x16x32_bf16(a, ba, aA, 0, 0, 0);
                aB = __builtin_amdgcn_mfma_f32_16x16x32_bf16(a, bb, aB, 0, 0, 0);
            }
#pragma unroll
            for (int r = 0; r < 4; ++r) {
                int e = chunkBase + mb * 16 + q * 4 + r;
                if (e < NEdges) {
                    float xa = aA[r] + b1a;
                    float xb = aB[r] + b1b;
                    float sa = xa * __builtin_amdgcn_rcpf(1.0f + __expf(-xa));
                    float sb = xb * __builtin_amdgcn_rcpf(1.0f + __expf(-xb));
                    hid[e * 128 + w * 16 + l15]      = f2bf_hw(sa);
                    hid[e * 128 + 64 + w * 16 + l15] = f2bf_hw(sb);
                }
            }
        }
        __syncthreads();
    }
}

// ---------------- K3: out = hid @ W2 + b2  (fp32 output) ----------------
__global__ __launch_bounds__(256) void k_elin2(
    const unsigned short* __restrict__ hid, const unsigned short* __restrict__ WT2,
    const float* __restrict__ b2, float* __restrict__ out) {
    const int t = threadIdx.x;
    const int w = t >> 6;
    const int l = t & 63;
    const int l15 = l & 15, q = l >> 4;
    const int rb = blockIdx.x * 64 + w * 16;   // NE = 3125*64 exactly, no tail

    f32x4 acc[9];
#pragma unroll
    for (int nb = 0; nb < 9; ++nb) acc[nb] = (f32x4){0.f, 0.f, 0.f, 0.f};

#pragma unroll
    for (int kb = 0; kb < 4; ++kb) {
        s16x8 a = *(const s16x8*)(hid + (rb + l15) * 128 + kb * 32 + q * 8);
#pragma unroll
        for (int nb = 0; nb < 9; ++nb) {
            s16x8 b = *(const s16x8*)(WT2 + (nb * 16 + l15) * 128 + kb * 32 + q * 8);
            acc[nb] = __builtin_amdgcn_mfma_f32_16x16x32_bf16(a, b, acc[nb], 0, 0, 0);
        }
    }
#pragma unroll
    for (int nb = 0; nb < 9; ++nb) {
        int n = nb * 16 + l15;
        float bb = b2[n];
#pragma unroll
        for (int r = 0; r < 4; ++r) {
            int e = rb + q * 4 + r;
            out[e * 144 + n] = acc[nb][r] + bb;
        }
    }
}

// ---------------- launch ----------------
extern "C" void kernel_launch(void* const* d_in, const int* in_sizes, int n_in,
                              void* d_out, int out_size, void* d_ws, size_t ws_size,
                              hipStream_t stream) {
    const float* atom = (const float*)d_in[0];
    const float* edge = (const float*)d_in[1];
    const int*   sai  = (const int*)d_in[2];
    const int*   sei  = (const int*)d_in[3];
    const float* ang  = (const float*)d_in[4];
    const int*   sidx = (const int*)d_in[5];
    const float* dist = (const float*)d_in[6];
    const float* Wf   = (const float*)d_in[7];
    const float* bfv  = (const float*)d_in[8];
    const float* Ws   = (const float*)d_in[9];
    const float* bsv  = (const float*)d_in[10];
    const float* W1   = (const float*)d_in[11];
    const float* b1   = (const float*)d_in[12];
    const float* W2   = (const float*)d_in[13];
    const float* b2   = (const float*)d_in[14];
    float* out = (float*)d_out;

    // workspace layout
    const size_t AGG_BYTES = (size_t)2 * NEdges * 64 * sizeof(float);     // 102,400,000
    const size_t HID_OFF   = AGG_BYTES;                                   // bf16 hid: 51,200,000
    const size_t WTFS_OFF  = HID_OFF + (size_t)NEdges * 128 * 2;
    const size_t WT1_OFF   = WTFS_OFF + 128 * 256 * 2;                    // WTfs: 65,536 B
    const size_t WT2_OFF   = WT1_OFF + 128 * 768 * 2;                     // WT1: 196,608 B
    const size_t NEEDED    = WT2_OFF + 144 * 128 * 2;                     // WT2: 36,864 B
    if (ws_size < NEEDED) return;   // diagnostic: output stays 0 -> absmax == max|ref|

    char* ws = (char*)d_ws;
    float* aggf = (float*)ws;
    unsigned short* hid  = (unsigned short*)(ws + HID_OFF);
    unsigned short* WTfs = (unsigned short*)(ws + WTFS_OFF);
    unsigned short* WT1  = (unsigned short*)(ws + WT1_OFF);
    unsigned short* WT2  = (unsigned short*)(ws + WT2_OFF);

    hipMemsetAsync(aggf, 0, AGG_BYTES, stream);
    k_prep<<<584, 256, 0, stream>>>(Wf, Ws, W1, W2, WTfs, WT1, WT2);
    k_gate<<<(NSubs + 255) / 256, 256, 0, stream>>>(atom, edge, sai, sei, ang, sidx, dist,
                                                    bfv, bsv, WTfs, aggf);
    k_elin1<<<(NEdges + 127) / 128, 256, 0, stream>>>(aggf, edge, WT1, b1, hid);
    k_elin2<<<NEdges / 64, 256, 0, stream>>>(hid, WT2, b2, out);
}

// Round 4
// 805.854 us; speedup vs baseline: 1.3104x; 1.0211x over previous
//
#include <hip/hip_runtime.h>
#include <stdint.h>

// ---- problem constants ----
#define NAtoms   50000
#define NEdges   200000
#define NSubs    1000000
#define KP1      776      // k_elin1 LDS row pitch (bf16 elems), K=768: 1552 B = odd*16
#define GCH      32       // k_gate chunk rows (fp32 tile in LDS)

// dtype model (validated): float tensors fp32, indices int32, OUTPUT fp32.

typedef short  s16x8 __attribute__((ext_vector_type(8)));
typedef unsigned short u16x8 __attribute__((ext_vector_type(8)));
typedef float  f32x4 __attribute__((ext_vector_type(4)));

__device__ __forceinline__ float bf2f(unsigned short u) {
    union { unsigned int i; float f; } v; v.i = ((unsigned int)u) << 16; return v.f;
}
// manual RNE (kept for k_prep; bit-identical to HW cvt)
__device__ __forceinline__ unsigned short f2bf(float f) {
    union { float f; unsigned int i; } v; v.f = f;
    unsigned int x = v.i;
    unsigned int r = (x + 0x7fffu + ((x >> 16) & 1u)) >> 16;   // RNE
    return (unsigned short)r;
}
// HW conversion: compiles to v_cvt_pk_bf16_f32 (RNE) on gfx950
__device__ __forceinline__ unsigned short f2bf_hw(float f) {
    union { __bf16 h; unsigned short u; } v; v.h = (__bf16)f; return v.u;
}
__device__ __forceinline__ s16x8 pk_bf16x8(f32x4 a, f32x4 b) {
    union { u16x8 u; s16x8 s; } o;
    o.u[0] = f2bf_hw(a[0]); o.u[1] = f2bf_hw(a[1]); o.u[2] = f2bf_hw(a[2]); o.u[3] = f2bf_hw(a[3]);
    o.u[4] = f2bf_hw(b[0]); o.u[5] = f2bf_hw(b[1]); o.u[6] = f2bf_hw(b[2]); o.u[7] = f2bf_hw(b[3]);
    return o.s;
}

// async global -> LDS, 16 B per lane; dest is wave-uniform base + lane*16
typedef const __attribute__((address_space(1))) void* as1_cvp;
typedef __attribute__((address_space(3))) void* as3_vp;
__device__ __forceinline__ void gll16(const void* g, void* l) {
    __builtin_amdgcn_global_load_lds((as1_cvp)g, (as3_vp)l, 16, 0, 0);
}

// ---------------- K0: fp32 weights -> bf16 n-major layouts in ws ----------------
__global__ void k_prep(const float* __restrict__ Wf, const float* __restrict__ Ws,
                       const float* __restrict__ W1, const float* __restrict__ W2,
                       unsigned short* __restrict__ WTfs, unsigned short* __restrict__ WT1,
                       unsigned short* __restrict__ WT2) {
    int id = blockIdx.x * 256 + threadIdx.x;
    if (id < 32768) {
        int k = id & 255, n = id >> 8;
        WTfs[n * 256 + k] = f2bf((n < 64) ? Wf[k * 64 + n] : Ws[k * 64 + (n - 64)]);
    } else if (id < 131072) {
        int m = id - 32768;                  // [0, 98304) = 128 n * 768 k
        int n = m / 768, k = m - n * 768;
        int seg = k >> 8, kk = k & 255;
        float w = (kk < 240) ? W1[kk * 128 + n] : 0.0f;
        unsigned short hi = f2bf(w);
        WT1[n * 768 + k] = (seg < 2) ? hi : f2bf(w - bf2f(hi));
    } else if (id < 149504) {
        int m = id - 131072;                 // [0, 18432) = 144 n * 128 k
        int k = m & 127, n = m >> 7;
        WT2[n * 128 + k] = f2bf(W2[k * 144 + n]);
    }
}

// ---------------- K1: double-buffered pipelined gather -> MFMA gate -> atomic scatter ----------
// Schedule per iteration c (T3/T4 counted-vmcnt pattern, raw s_barrier, never drain to 0):
//   ISSUE gll(c+1) -> buf[(c+1)&1]      (WAR-safe: compute(c-1) barrier'd)
//   LOADIDX(c+2)                        (scalar s_loads, lgkmcnt)
//   s_waitcnt vmcnt(8)                  (retires gll(c) + atomics(c-1); gll(c+1) stays in flight)
//   s_waitcnt lgkmcnt(0); s_barrier
//   COMPUTE(c) from buf[c&1]; s_barrier
__global__ __launch_bounds__(256) void k_gate(
    const float* __restrict__ atom, const float* __restrict__ edge,
    const int* __restrict__ sai, const int* __restrict__ sei,
    const float* __restrict__ ang, const int* __restrict__ sidx_g,
    const float* __restrict__ dist,
    const float* __restrict__ bfv, const float* __restrict__ bsv,
    const unsigned short* __restrict__ WTfs, float* __restrict__ aggf) {
    __shared__ __align__(16) float ztf[2][GCH * 256];   // 2 x 32 KiB fp32 tile
    __shared__ float decf[2][GCH];
    __shared__ int   sidx[2][GCH];

    const int t = threadIdx.x;
    const int w = t >> 6;          // wave id: owns F cols [16w,16w+16) and S cols [64+16w,...)
    const int l = t & 63;
    const int l15 = l & 15, q = l >> 4;
    const int rowBlock = blockIdx.x << 8;   // 256 rows per block

    // B fragments cached in registers/AGPRs for the whole block
    s16x8 bF[8], bS[8];
    {
        const unsigned short* pf = WTfs + (w * 16 + l15) * 256 + q * 8;
        const unsigned short* ps = WTfs + (64 + w * 16 + l15) * 256 + q * 8;
#pragma unroll
        for (int kb = 0; kb < 8; ++kb) {
            bF[kb] = *(const s16x8*)(pf + kb * 32);
            bS[kb] = *(const s16x8*)(ps + kb * 32);
        }
    }
    const float bfj = bfv[w * 16 + l15];
    const float bsj = bsv[w * 16 + l15];

    // 2-deep index pipeline (wave-uniform; all indices compile-time after full unroll)
    int sA[2][8], i0A[2][8], i1A[2][8], e2A[2][8];

    auto LOADIDX = [&](int cc, int par) {
#pragma unroll
        for (int p = 0; p < 8; ++p) {
            int s = rowBlock + cc * GCH + w * 8 + p;
            s = (s < NSubs) ? s : (NSubs - 1);          // clamp: loads always valid
            s = __builtin_amdgcn_readfirstlane(s);
            sA[par][p] = s;
            i0A[par][p] = sai[2 * s];
            i1A[par][p] = sai[2 * s + 1];
            e2A[par][p] = sei[s];
        }
    };
    auto ISSUE = [&](int par) {
#pragma unroll
        for (int p = 0; p < 8; ++p) {
            const int lr = w * 8 + p;
            const int G = l ^ (lr & 7);                 // pre-swizzled source granule
            const float* srcA = atom + (size_t)i0A[par][p] * 64  + (G      ) * 4;
            const float* srcB = atom + (size_t)i1A[par][p] * 64  + (G - 16 ) * 4;
            const float* srcC = edge + (size_t)e2A[par][p] * 112 + (G - 32 ) * 4;
            const float* srcD = ang  + (size_t)sA[par][p]  * 16  + (G - 60 ) * 4;
            const float* src = (G < 16) ? srcA : (G < 32) ? srcB : (G < 60) ? srcC : srcD;
            gll16(src, &ztf[par][lr * 256]);
            // per-row epilogue scalars (uniform s_loads, lgkmcnt)
            float d = dist[e2A[par][p]];
            float dc = __expf(-d * d * (1.0f / 18.0f));
            int sv = sidx_g[sA[par][p]];
            if (l == 0) { decf[par][lr] = dc; sidx[par][lr] = sv; }
        }
    };
    auto COMPUTE = [&](int cc, int par) {
        const int chunkBase = rowBlock + cc * GCH;
#pragma unroll
        for (int mb = 0; mb < 2; ++mb) {
            f32x4 aF = {0.f, 0.f, 0.f, 0.f}, aS = {0.f, 0.f, 0.f, 0.f};
            const int row = mb * 16 + l15;
            const int sw = row & 7;
            const float* zrow = &ztf[par][row * 256];
#pragma unroll
            for (int kb = 0; kb < 8; ++kb) {
                const int g0 = kb * 8 + q * 2;
                f32x4 x0 = *(const f32x4*)(zrow + (((g0    ) ^ sw) << 2));
                f32x4 x1 = *(const f32x4*)(zrow + (((g0 + 1) ^ sw) << 2));
                s16x8 a = pk_bf16x8(x0, x1);
                aF = __builtin_amdgcn_mfma_f32_16x16x32_bf16(a, bF[kb], aF, 0, 0, 0);
                aS = __builtin_amdgcn_mfma_f32_16x16x32_bf16(a, bS[kb], aS, 0, 0, 0);
            }
#pragma unroll
            for (int r = 0; r < 4; ++r) {
                int lr = mb * 16 + q * 4 + r;
                int s = chunkBase + lr;
                if (s < NSubs) {
                    float xf = aF[r] + bfj;
                    float xs = aS[r] + bsj;
                    float sig = __builtin_amdgcn_rcpf(1.0f + __expf(-xf));
                    float sp  = (xs > 20.0f) ? xs : __logf(1.0f + __expf(xs));
                    float val = sig * sp * decf[par][lr];
                    unsafeAtomicAdd(aggf + (size_t)sidx[par][lr] * 64 + (w * 16 + l15), val);
                }
            }
        }
    };

    // ---- prologue ----
    LOADIDX(0, 0);
    ISSUE(0);               // gll(0) -> buf0
    LOADIDX(1, 1);

    // ---- main pipelined loop: compute chunks 0..6, prefetch 1..7 ----
#pragma unroll
    for (int c = 0; c < 7; ++c) {
        const int pc = c & 1;
        const int pn = (c + 1) & 1;
        ISSUE(pn);                              // gll(c+1) -> buf[pn] (uses idx set pn)
        if (c + 2 < 8) LOADIDX(c + 2, pc);      // idx set pc is free (idx(c) consumed)
        asm volatile("s_waitcnt vmcnt(8)" ::: "memory");   // gll(c) + atomics(c-1) retired
        asm volatile("s_waitcnt lgkmcnt(0)" ::: "memory"); // idx s_loads + decf/sidx ds_writes done
        __builtin_amdgcn_sched_barrier(0);
        __builtin_amdgcn_s_barrier();
        __builtin_amdgcn_sched_barrier(0);
        COMPUTE(c, pc);
        asm volatile("s_waitcnt lgkmcnt(0)" ::: "memory"); // all ds_reads of buf[pc] retired
        __builtin_amdgcn_s_barrier();                      // buf[pc] free for overwrite next iter
        __builtin_amdgcn_sched_barrier(0);
    }
    // ---- epilogue: chunk 7 ----
    asm volatile("s_waitcnt vmcnt(0) lgkmcnt(0)" ::: "memory");
    __builtin_amdgcn_sched_barrier(0);
    __builtin_amdgcn_s_barrier();
    __builtin_amdgcn_sched_barrier(0);
    COMPUTE(7, 1);
}

// ---------------- K2: h=[agg|agg|edge] -> bf16x3 -> silu(h@W1+b1) -> hid(bf16) ----------------
// A row (K=768): [h_hi(256) | h_lo(256) | h_hi(256)], h = [aggf 128 | edge 112 | 0 pad 16]
__global__ __launch_bounds__(256) void k_elin1(
    const float* __restrict__ aggf, const float* __restrict__ edge,
    const unsigned short* __restrict__ WT1, const float* __restrict__ b1,
    unsigned short* __restrict__ hid) {
    __shared__ __align__(16) unsigned short zt[32 * KP1];

    const int t = threadIdx.x;
    const int w = t >> 6;
    const int l = t & 63;
    const int l15 = l & 15, q = l >> 4;
    const int rowBlock = blockIdx.x << 7;   // 128 rows per block

    const float b1a = b1[w * 16 + l15];
    const float b1b = b1[64 + w * 16 + l15];

    const int cg = t & 31;                  // column-group: loop-invariant per thread
    const int g  = t >> 5;

    for (int c = 0; c < 4; ++c) {
        const int chunkBase = rowBlock + c * 32;
        // ---- stage 32 rows: burst all 8 loads into regs, then convert ----
        f32x4 v0a[4], v1a[4];
#pragma unroll
        for (int i = 0; i < 4; ++i) {
            int lr = i * 8 + g;
            int e = chunkBase + lr;
            int ec = (e < NEdges) ? e : (NEdges - 1);   // clamp: loads always valid
            f32x4 v0 = {0.f, 0.f, 0.f, 0.f}, v1 = {0.f, 0.f, 0.f, 0.f};
            if (cg < 16) {
                const float* src = aggf + (size_t)ec * 128 + cg * 8;
                v0 = *(const f32x4*)src; v1 = *(const f32x4*)(src + 4);
            } else if (cg < 30) {
                const float* src = edge + (size_t)ec * 112 + (cg - 16) * 8;
                v0 = *(const f32x4*)src; v1 = *(const f32x4*)(src + 4);
            }
            v0a[i] = v0; v1a[i] = v1;
        }
#pragma unroll
        for (int i = 0; i < 4; ++i) {
            int lr = i * 8 + g;
            u16x8 hi, lo;
#pragma unroll
            for (int j = 0; j < 4; ++j) {
                hi[j] = f2bf_hw(v0a[i][j]);     lo[j] = f2bf_hw(v0a[i][j] - bf2f(hi[j]));
                hi[4 + j] = f2bf_hw(v1a[i][j]); lo[4 + j] = f2bf_hw(v1a[i][j] - bf2f(hi[4 + j]));
            }
            unsigned short* zrow = zt + lr * KP1;
            *(u16x8*)(zrow + cg * 8) = hi;
            *(u16x8*)(zrow + 256 + cg * 8) = lo;
            *(u16x8*)(zrow + 512 + cg * 8) = hi;
        }
        __syncthreads();
        // ---- MFMA: 2 m-batches of 16 rows, K=768; B-frags streamed from global (L1/L2) ----
#pragma unroll
        for (int mb = 0; mb < 2; ++mb) {
            f32x4 aA = {0.f, 0.f, 0.f, 0.f}, aB = {0.f, 0.f, 0.f, 0.f};
            const unsigned short* zb = zt + (mb * 16 + l15) * KP1 + q * 8;
            const unsigned short* pa = WT1 + (w * 16 + l15) * 768 + q * 8;
            const unsigned short* pb = WT1 + (64 + w * 16 + l15) * 768 + q * 8;
#pragma unroll
            for (int kb = 0; kb < 24; ++kb) {
                s16x8 a  = *(const s16x8*)(zb + kb * 32);
                s16x8 ba = *(const s16x8*)(pa + kb * 32);
                s16x8 bb = *(const s16x8*)(pb + kb * 32);
                aA = __builtin_amdgcn_mfma_f32_16x16x32_bf16(a, ba, aA, 0, 0, 0);
                aB = __builtin_amdgcn_mfma_f32_16x16x32_bf16(a, bb, aB, 0, 0, 0);
            }
#pragma unroll
            for (int r = 0; r < 4; ++r) {
                int e = chunkBase + mb * 16 + q * 4 + r;
                if (e < NEdges) {
                    float xa = aA[r] + b1a;
                    float xb = aB[r] + b1b;
                    float sa = xa * __builtin_amdgcn_rcpf(1.0f + __expf(-xa));
                    float sb = xb * __builtin_amdgcn_rcpf(1.0f + __expf(-xb));
                    hid[e * 128 + w * 16 + l15]      = f2bf_hw(sa);
                    hid[e * 128 + 64 + w * 16 + l15] = f2bf_hw(sb);
                }
            }
        }
        __syncthreads();
    }
}

// ---------------- K3: out = hid @ W2 + b2  (fp32 output) ----------------
__global__ __launch_bounds__(256) void k_elin2(
    const unsigned short* __restrict__ hid, const unsigned short* __restrict__ WT2,
    const float* __restrict__ b2, float* __restrict__ out) {
    const int t = threadIdx.x;
    const int w = t >> 6;
    const int l = t & 63;
    const int l15 = l & 15, q = l >> 4;
    const int rb = blockIdx.x * 64 + w * 16;   // NE = 3125*64 exactly, no tail

    f32x4 acc[9];
#pragma unroll
    for (int nb = 0; nb < 9; ++nb) acc[nb] = (f32x4){0.f, 0.f, 0.f, 0.f};

#pragma unroll
    for (int kb = 0; kb < 4; ++kb) {
        s16x8 a = *(const s16x8*)(hid + (rb + l15) * 128 + kb * 32 + q * 8);
#pragma unroll
        for (int nb = 0; nb < 9; ++nb) {
            s16x8 b = *(const s16x8*)(WT2 + (nb * 16 + l15) * 128 + kb * 32 + q * 8);
            acc[nb] = __builtin_amdgcn_mfma_f32_16x16x32_bf16(a, b, acc[nb], 0, 0, 0);
        }
    }
#pragma unroll
    for (int nb = 0; nb < 9; ++nb) {
        int n = nb * 16 + l15;
        float bb = b2[n];
#pragma unroll
        for (int r = 0; r < 4; ++r) {
            int e = rb + q * 4 + r;
            out[e * 144 + n] = acc[nb][r] + bb;
        }
    }
}

// ---------------- launch ----------------
extern "C" void kernel_launch(void* const* d_in, const int* in_sizes, int n_in,
                              void* d_out, int out_size, void* d_ws, size_t ws_size,
                              hipStream_t stream) {
    const float* atom = (const float*)d_in[0];
    const float* edge = (const float*)d_in[1];
    const int*   sai  = (const int*)d_in[2];
    const int*   sei  = (const int*)d_in[3];
    const float* ang  = (const float*)d_in[4];
    const int*   sidx = (const int*)d_in[5];
    const float* dist = (const float*)d_in[6];
    const float* Wf   = (const float*)d_in[7];
    const float* bfv  = (const float*)d_in[8];
    const float* Ws   = (const float*)d_in[9];
    const float* bsv  = (const float*)d_in[10];
    const float* W1   = (const float*)d_in[11];
    const float* b1   = (const float*)d_in[12];
    const float* W2   = (const float*)d_in[13];
    const float* b2   = (const float*)d_in[14];
    float* out = (float*)d_out;

    // workspace layout
    const size_t AGG_BYTES = (size_t)2 * NEdges * 64 * sizeof(float);     // 102,400,000
    const size_t HID_OFF   = AGG_BYTES;                                   // bf16 hid: 51,200,000
    const size_t WTFS_OFF  = HID_OFF + (size_t)NEdges * 128 * 2;
    const size_t WT1_OFF   = WTFS_OFF + 128 * 256 * 2;                    // WTfs: 65,536 B
    const size_t WT2_OFF   = WT1_OFF + 128 * 768 * 2;                     // WT1: 196,608 B
    const size_t NEEDED    = WT2_OFF + 144 * 128 * 2;                     // WT2: 36,864 B
    if (ws_size < NEEDED) return;   // diagnostic: output stays 0 -> absmax == max|ref|

    char* ws = (char*)d_ws;
    float* aggf = (float*)ws;
    unsigned short* hid  = (unsigned short*)(ws + HID_OFF);
    unsigned short* WTfs = (unsigned short*)(ws + WTFS_OFF);
    unsigned short* WT1  = (unsigned short*)(ws + WT1_OFF);
    unsigned short* WT2  = (unsigned short*)(ws + WT2_OFF);

    hipMemsetAsync(aggf, 0, AGG_BYTES, stream);
    k_prep<<<584, 256, 0, stream>>>(Wf, Ws, W1, W2, WTfs, WT1, WT2);
    k_gate<<<(NSubs + 255) / 256, 256, 0, stream>>>(atom, edge, sai, sei, ang, sidx, dist,
                                                    bfv, bsv, WTfs, aggf);
    k_elin1<<<(NEdges + 127) / 128, 256, 0, stream>>>(aggf, edge, WT1, b1, hid);
    k_elin2<<<NEdges / 64, 256, 0, stream>>>(hid, WT2, b2, out);
}

// Round 7
// 672.027 us; speedup vs baseline: 1.5713x; 1.1991x over previous
//
#include <hip/hip_runtime.h>
#include <stdint.h>

// ---- problem constants ----
#define NAtoms   50000
#define NEdges   200000
#define NSubs    1000000
#define KP1      776      // k_elin1 LDS row pitch (bf16 elems), K=768: 1552 B = odd*16
#define GCH      32       // k_gate chunk rows (fp32 tile in LDS)

// dtype model (validated): float tensors fp32, indices int32, OUTPUT fp32.

typedef short  s16x8 __attribute__((ext_vector_type(8)));
typedef unsigned short u16x8 __attribute__((ext_vector_type(8)));
typedef float  f32x4 __attribute__((ext_vector_type(4)));
typedef int    i32x4 __attribute__((ext_vector_type(4)));

__device__ __forceinline__ float bf2f(unsigned short u) {
    union { unsigned int i; float f; } v; v.i = ((unsigned int)u) << 16; return v.f;
}
// manual RNE (kept for k_prep; bit-identical to HW cvt)
__device__ __forceinline__ unsigned short f2bf(float f) {
    union { float f; unsigned int i; } v; v.f = f;
    unsigned int x = v.i;
    unsigned int r = (x + 0x7fffu + ((x >> 16) & 1u)) >> 16;   // RNE
    return (unsigned short)r;
}
// HW conversion: compiles to v_cvt_pk_bf16_f32 (RNE) on gfx950
__device__ __forceinline__ unsigned short f2bf_hw(float f) {
    union { __bf16 h; unsigned short u; } v; v.h = (__bf16)f; return v.u;
}
__device__ __forceinline__ s16x8 pk_bf16x8(f32x4 a, f32x4 b) {
    union { u16x8 u; s16x8 s; } o;
    o.u[0] = f2bf_hw(a[0]); o.u[1] = f2bf_hw(a[1]); o.u[2] = f2bf_hw(a[2]); o.u[3] = f2bf_hw(a[3]);
    o.u[4] = f2bf_hw(b[0]); o.u[5] = f2bf_hw(b[1]); o.u[6] = f2bf_hw(b[2]); o.u[7] = f2bf_hw(b[3]);
    return o.s;
}

// async global -> LDS, 16 B per lane; dest is wave-uniform base + lane*16
typedef const __attribute__((address_space(1))) void* as1_cvp;
typedef __attribute__((address_space(3))) void* as3_vp;
__device__ __forceinline__ void gll16(const void* g, void* l) {
    __builtin_amdgcn_global_load_lds((as1_cvp)g, (as3_vp)l, 16, 0, 0);
}

// ---------------- K0: fp32 weights -> bf16 n-major layouts in ws ----------------
__global__ void k_prep(const float* __restrict__ Wf, const float* __restrict__ Ws,
                       const float* __restrict__ W1, const float* __restrict__ W2,
                       unsigned short* __restrict__ WTfs, unsigned short* __restrict__ WT1,
                       unsigned short* __restrict__ WT2) {
    int id = blockIdx.x * 256 + threadIdx.x;
    if (id < 32768) {
        int k = id & 255, n = id >> 8;
        WTfs[n * 256 + k] = f2bf((n < 64) ? Wf[k * 64 + n] : Ws[k * 64 + (n - 64)]);
    } else if (id < 131072) {
        int m = id - 32768;                  // [0, 98304) = 128 n * 768 k
        int n = m / 768, k = m - n * 768;
        int seg = k >> 8, kk = k & 255;
        float w = (kk < 240) ? W1[kk * 128 + n] : 0.0f;
        unsigned short hi = f2bf(w);
        WT1[n * 768 + k] = (seg < 2) ? hi : f2bf(w - bf2f(hi));
    } else if (id < 149504) {
        int m = id - 131072;                 // [0, 18432) = 144 n * 128 k
        int k = m & 127, n = m >> 7;
        WT2[n * 128 + k] = f2bf(W2[k * 144 + n]);
    }
}

// ---------------- K0b: dec[s] = exp(-dist[sei[s]]^2/18) -- kills the 2-level chain in k_gate ---
__global__ __launch_bounds__(256) void k_dec(const int* __restrict__ sei,
                                             const float* __restrict__ dist,
                                             float* __restrict__ dec) {
    int s = blockIdx.x * 256 + threadIdx.x;
    if (s < NSubs) {
        float d = dist[sei[s]];
        dec[s] = __expf(-d * d * (1.0f / 18.0f));
    }
}

// ---------------- K1: depth-1 pipelined gather -> MFMA gate -> atomic scatter -------------------
// Per-iteration vmem FIFO (in-order retire): [dec(c):4][gll(c):8][atom(c-1):8][dec(c+1):4][gll(c+1):8]
// wait vmcnt(20) retires dec(c)+gll(c) (issued one full compute-phase ago -> ~free) while
// atomics(c-1) and next-chunk loads STAY IN FLIGHT. No lgkmcnt(0) before the compute barrier:
// index s_loads are 2 iterations deep, dec/sidx come from registers, no ds_writes exist.
// Atomic count is exec-uniform (8/wave always: masked rows add 0.0f at a safe offset).
__global__ __launch_bounds__(256) void k_gate(
    const float* __restrict__ atom, const float* __restrict__ edge,
    const int* __restrict__ sai, const int* __restrict__ sei,
    const float* __restrict__ ang, const int* __restrict__ sidx_g,
    const float* __restrict__ decg,
    const float* __restrict__ bfv, const float* __restrict__ bsv,
    const unsigned short* __restrict__ WTfs, float* __restrict__ aggf) {
    __shared__ __align__(16) float ztf[2][GCH * 256];   // 2 x 32 KiB fp32 tile

    const int t = threadIdx.x;
    const int w = t >> 6;          // wave id: owns F cols [16w,16w+16) and S cols [64+16w,...)
    const int l = t & 63;
    const int l15 = l & 15, q = l >> 4;
    const int rowBlock = blockIdx.x << 8;   // 256 rows per block

    // B fragments cached in registers/AGPRs for the whole block
    s16x8 bF[8], bS[8];
    {
        const unsigned short* pf = WTfs + (w * 16 + l15) * 256 + q * 8;
        const unsigned short* ps = WTfs + (64 + w * 16 + l15) * 256 + q * 8;
#pragma unroll
        for (int kb = 0; kb < 8; ++kb) {
            bF[kb] = *(const s16x8*)(pf + kb * 32);
            bS[kb] = *(const s16x8*)(ps + kb * 32);
        }
    }
    const float bfj = bfv[w * 16 + l15];
    const float bsj = bsv[w * 16 + l15];

    // 2-deep index pipeline (wave-uniform scalars; static indexing via full unroll)
    int iS[2][8], iI0[2][8], iI1[2][8], iE2[2][8];
    // 1-deep dec/sidx register pipeline (per-lane vector loads, contiguous in s)
    f32x4 dA[2], dB[2];
    i32x4 xA[2], xB[2];

    auto LOADIDX = [&](int cc, int par) {
#pragma unroll
        for (int p = 0; p < 8; ++p) {
            int s = rowBlock + cc * GCH + w * 8 + p;
            s = (s < NSubs) ? s : (NSubs - 1);          // clamp: loads always valid
            s = __builtin_amdgcn_readfirstlane(s);
            iS[par][p] = s;
            iI0[par][p] = sai[2 * s];
            iI1[par][p] = sai[2 * s + 1];
            iE2[par][p] = sei[s];
        }
    };
    auto DECLOAD = [&](int cc, int par) {
        int b0 = rowBlock + cc * GCH;
        int base = (b0 <= NSubs - GCH) ? b0 : (NSubs - GCH);   // wave-uniform clamp, in-bounds
        dA[par] = *(const f32x4*)(decg + base + q * 4);
        dB[par] = *(const f32x4*)(decg + base + 16 + q * 4);
        xA[par] = *(const i32x4*)(sidx_g + base + q * 4);
        xB[par] = *(const i32x4*)(sidx_g + base + 16 + q * 4);
    };
    auto ISSUE = [&](int par) {
#pragma unroll
        for (int p = 0; p < 8; ++p) {
            const int lr = w * 8 + p;
            const int G = l ^ (lr & 7);                 // pre-swizzled source granule
            const float* srcA = atom + (size_t)iI0[par][p] * 64  + (G      ) * 4;
            const float* srcB = atom + (size_t)iI1[par][p] * 64  + (G - 16 ) * 4;
            const float* srcC = edge + (size_t)iE2[par][p] * 112 + (G - 32 ) * 4;
            const float* srcD = ang  + (size_t)iS[par][p]  * 16  + (G - 60 ) * 4;
            const float* src = (G < 16) ? srcA : (G < 32) ? srcB : (G < 60) ? srcC : srcD;
            gll16(src, &ztf[par][lr * 256]);
        }
    };
    auto COMPUTE = [&](int cc, int par) {
        const int chunkBase = rowBlock + cc * GCH;
#pragma unroll
        for (int mb = 0; mb < 2; ++mb) {
            f32x4 aF = {0.f, 0.f, 0.f, 0.f}, aS = {0.f, 0.f, 0.f, 0.f};
            const int row = mb * 16 + l15;
            const int sw = row & 7;
            const float* zrow = &ztf[par][row * 256];
#pragma unroll
            for (int kb = 0; kb < 8; ++kb) {
                const int g0 = kb * 8 + q * 2;
                f32x4 x0 = *(const f32x4*)(zrow + (((g0    ) ^ sw) << 2));
                f32x4 x1 = *(const f32x4*)(zrow + (((g0 + 1) ^ sw) << 2));
                s16x8 a = pk_bf16x8(x0, x1);
                aF = __builtin_amdgcn_mfma_f32_16x16x32_bf16(a, bF[kb], aF, 0, 0, 0);
                aS = __builtin_amdgcn_mfma_f32_16x16x32_bf16(a, bS[kb], aS, 0, 0, 0);
            }
#pragma unroll
            for (int r = 0; r < 4; ++r) {
                int lr = mb * 16 + q * 4 + r;
                int s = chunkBase + lr;
                bool ok = (s < NSubs);
                float decv = mb ? dB[par][r] : dA[par][r];
                int   sxv  = mb ? xB[par][r] : xA[par][r];
                float xf = aF[r] + bfj;
                float xs = aS[r] + bsj;
                float sig = __builtin_amdgcn_rcpf(1.0f + __expf(-xf));
                float sp  = (xs > 20.0f) ? xs : __logf(1.0f + __expf(xs));
                float val = ok ? (sig * sp * decv) : 0.0f;
                size_t off = ok ? ((size_t)sxv * 64 + (w * 16 + l15))
                                : (size_t)(w * 16 + l15);
                unsafeAtomicAdd(aggf + off, val);   // uniform: 8 atomic insts per wave per chunk
            }
        }
    };

    // ---- prologue ----
    LOADIDX(0, 0);
    LOADIDX(1, 1);
    DECLOAD(0, 0);
    ISSUE(0);               // gll(0) -> buf0

    // ---- main loop, fully unrolled (static parity + exact vmcnt counts) ----
#pragma unroll
    for (int c = 0; c < 8; ++c) {
        const int pc = c & 1;
        const int pn = (c + 1) & 1;
        if (c + 1 < 8) { DECLOAD(c + 1, pn); ISSUE(pn); }
        if (c + 2 < 8) LOADIDX(c + 2, pc);
        // retire dec(c)+gll(c) only; atomics(c-1), dec(c+1), gll(c+1) stay in flight
        if (c == 0)      asm volatile("s_waitcnt vmcnt(12)" ::: "memory");
        else if (c < 7)  asm volatile("s_waitcnt vmcnt(20)" ::: "memory");
        else             asm volatile("s_waitcnt vmcnt(8)"  ::: "memory");
        __builtin_amdgcn_sched_barrier(0);
        __builtin_amdgcn_s_barrier();
        __builtin_amdgcn_sched_barrier(0);
        COMPUTE(c, pc);
        asm volatile("s_waitcnt lgkmcnt(0)" ::: "memory"); // this wave's ds_reads of buf[pc] done
        __builtin_amdgcn_s_barrier();                      // buf[pc] free for overwrite next iter
        __builtin_amdgcn_sched_barrier(0);
    }
}

// ---------------- K2: h=[agg|agg|edge] -> bf16x3 -> silu(h@W1+b1) -> hid(bf16) ----------------
// A row (K=768): [h_hi(256) | h_lo(256) | h_hi(256)], h = [aggf 128 | edge 112 | 0 pad 16]
__global__ __launch_bounds__(256) void k_elin1(
    const float* __restrict__ aggf, const float* __restrict__ edge,
    const unsigned short* __restrict__ WT1, const float* __restrict__ b1,
    unsigned short* __restrict__ hid) {
    __shared__ __align__(16) unsigned short zt[32 * KP1];

    const int t = threadIdx.x;
    const int w = t >> 6;
    const int l = t & 63;
    const int l15 = l & 15, q = l >> 4;
    const int rowBlock = blockIdx.x << 7;   // 128 rows per block

    const float b1a = b1[w * 16 + l15];
    const float b1b = b1[64 + w * 16 + l15];

    const int cg = t & 31;                  // column-group: loop-invariant per thread
    const int g  = t >> 5;

    for (int c = 0; c < 4; ++c) {
        const int chunkBase = rowBlock + c * 32;
        // ---- stage 32 rows: burst all 8 loads into regs, then convert ----
        f32x4 v0a[4], v1a[4];
#pragma unroll
        for (int i = 0; i < 4; ++i) {
            int lr = i * 8 + g;
            int e = chunkBase + lr;
            int ec = (e < NEdges) ? e : (NEdges - 1);   // clamp: loads always valid
            f32x4 v0 = {0.f, 0.f, 0.f, 0.f}, v1 = {0.f, 0.f, 0.f, 0.f};
            if (cg < 16) {
                const float* src = aggf + (size_t)ec * 128 + cg * 8;
                v0 = *(const f32x4*)src; v1 = *(const f32x4*)(src + 4);
            } else if (cg < 30) {
                const float* src = edge + (size_t)ec * 112 + (cg - 16) * 8;
                v0 = *(const f32x4*)src; v1 = *(const f32x4*)(src + 4);
            }
            v0a[i] = v0; v1a[i] = v1;
        }
#pragma unroll
        for (int i = 0; i < 4; ++i) {
            int lr = i * 8 + g;
            u16x8 hi, lo;
#pragma unroll
            for (int j = 0; j < 4; ++j) {
                hi[j] = f2bf_hw(v0a[i][j]);     lo[j] = f2bf_hw(v0a[i][j] - bf2f(hi[j]));
                hi[4 + j] = f2bf_hw(v1a[i][j]); lo[4 + j] = f2bf_hw(v1a[i][j] - bf2f(hi[4 + j]));
            }
            unsigned short* zrow = zt + lr * KP1;
            *(u16x8*)(zrow + cg * 8) = hi;
            *(u16x8*)(zrow + 256 + cg * 8) = lo;
            *(u16x8*)(zrow + 512 + cg * 8) = hi;
        }
        __syncthreads();
        // ---- MFMA: 2 m-batches of 16 rows, K=768; B-frags streamed from global (L1/L2) ----
#pragma unroll
        for (int mb = 0; mb < 2; ++mb) {
            f32x4 aA = {0.f, 0.f, 0.f, 0.f}, aB = {0.f, 0.f, 0.f, 0.f};
            const unsigned short* zb = zt + (mb * 16 + l15) * KP1 + q * 8;
            const unsigned short* pa = WT1 + (w * 16 + l15) * 768 + q * 8;
            const unsigned short* pb = WT1 + (64 + w * 16 + l15) * 768 + q * 8;
#pragma unroll
            for (int kb = 0; kb < 24; ++kb) {
                s16x8 a  = *(const s16x8*)(zb + kb * 32);
                s16x8 ba = *(const s16x8*)(pa + kb * 32);
                s16x8 bb = *(const s16x8*)(pb + kb * 32);
                aA = __builtin_amdgcn_mfma_f32_16x16x32_bf16(a, ba, aA, 0, 0, 0);
                aB = __builtin_amdgcn_mfma_f32_16x16x32_bf16(a, bb, aB, 0, 0, 0);
            }
#pragma unroll
            for (int r = 0; r < 4; ++r) {
                int e = chunkBase + mb * 16 + q * 4 + r;
                if (e < NEdges) {
                    float xa = aA[r] + b1a;
                    float xb = aB[r] + b1b;
                    float sa = xa * __builtin_amdgcn_rcpf(1.0f + __expf(-xa));
                    float sb = xb * __builtin_amdgcn_rcpf(1.0f + __expf(-xb));
                    hid[e * 128 + w * 16 + l15]      = f2bf_hw(sa);
                    hid[e * 128 + 64 + w * 16 + l15] = f2bf_hw(sb);
                }
            }
        }
        __syncthreads();
    }
}

// ---------------- K3: out = hid @ W2 + b2  (fp32 output) ----------------
__global__ __launch_bounds__(256) void k_elin2(
    const unsigned short* __restrict__ hid, const unsigned short* __restrict__ WT2,
    const float* __restrict__ b2, float* __restrict__ out) {
    const int t = threadIdx.x;
    const int w = t >> 6;
    const int l = t & 63;
    const int l15 = l & 15, q = l >> 4;
    const int rb = blockIdx.x * 64 + w * 16;   // NE = 3125*64 exactly, no tail

    f32x4 acc[9];
#pragma unroll
    for (int nb = 0; nb < 9; ++nb) acc[nb] = (f32x4){0.f, 0.f, 0.f, 0.f};

#pragma unroll
    for (int kb = 0; kb < 4; ++kb) {
        s16x8 a = *(const s16x8*)(hid + (rb + l15) * 128 + kb * 32 + q * 8);
#pragma unroll
        for (int nb = 0; nb < 9; ++nb) {
            s16x8 b = *(const s16x8*)(WT2 + (nb * 16 + l15) * 128 + kb * 32 + q * 8);
            acc[nb] = __builtin_amdgcn_mfma_f32_16x16x32_bf16(a, b, acc[nb], 0, 0, 0);
        }
    }
#pragma unroll
    for (int nb = 0; nb < 9; ++nb) {
        int n = nb * 16 + l15;
        float bb = b2[n];
#pragma unroll
        for (int r = 0; r < 4; ++r) {
            int e = rb + q * 4 + r;
            out[e * 144 + n] = acc[nb][r] + bb;
        }
    }
}

// ---------------- launch ----------------
extern "C" void kernel_launch(void* const* d_in, const int* in_sizes, int n_in,
                              void* d_out, int out_size, void* d_ws, size_t ws_size,
                              hipStream_t stream) {
    const float* atom = (const float*)d_in[0];
    const float* edge = (const float*)d_in[1];
    const int*   sai  = (const int*)d_in[2];
    const int*   sei  = (const int*)d_in[3];
    const float* ang  = (const float*)d_in[4];
    const int*   sidx = (const int*)d_in[5];
    const float* dist = (const float*)d_in[6];
    const float* Wf   = (const float*)d_in[7];
    const float* bfv  = (const float*)d_in[8];
    const float* Ws   = (const float*)d_in[9];
    const float* bsv  = (const float*)d_in[10];
    const float* W1   = (const float*)d_in[11];
    const float* b1   = (const float*)d_in[12];
    const float* W2   = (const float*)d_in[13];
    const float* b2   = (const float*)d_in[14];
    float* out = (float*)d_out;

    // workspace layout
    const size_t AGG_BYTES = (size_t)2 * NEdges * 64 * sizeof(float);     // 102,400,000
    const size_t HID_OFF   = AGG_BYTES;                                   // bf16 hid: 51,200,000
    const size_t WTFS_OFF  = HID_OFF + (size_t)NEdges * 128 * 2;
    const size_t WT1_OFF   = WTFS_OFF + 128 * 256 * 2;                    // WTfs: 65,536 B
    const size_t WT2_OFF   = WT1_OFF + 128 * 768 * 2;                     // WT1: 196,608 B
    const size_t NEEDED    = WT2_OFF + 144 * 128 * 2;                     // WT2: 36,864 B
    if (ws_size < NEEDED) return;   // diagnostic: output stays 0 -> absmax == max|ref|

    char* ws = (char*)d_ws;
    float* aggf = (float*)ws;
    unsigned short* hid  = (unsigned short*)(ws + HID_OFF);
    float* decg = (float*)(ws + HID_OFF);   // dec table (4 MB) aliases hid: disjoint lifetimes
    unsigned short* WTfs = (unsigned short*)(ws + WTFS_OFF);
    unsigned short* WT1  = (unsigned short*)(ws + WT1_OFF);
    unsigned short* WT2  = (unsigned short*)(ws + WT2_OFF);

    hipMemsetAsync(aggf, 0, AGG_BYTES, stream);
    k_prep<<<584, 256, 0, stream>>>(Wf, Ws, W1, W2, WTfs, WT1, WT2);
    k_dec<<<(NSubs + 255) / 256, 256, 0, stream>>>(sei, dist, decg);
    k_gate<<<(NSubs + 255) / 256, 256, 0, stream>>>(atom, edge, sai, sei, ang, sidx, decg,
                                                    bfv, bsv, WTfs, aggf);
    k_elin1<<<(NEdges + 127) / 128, 256, 0, stream>>>(aggf, edge, WT1, b1, hid);
    k_elin2<<<NEdges / 64, 256, 0, stream>>>(hid, WT2, b2, out);
}